// Round 12
// baseline (44.105 us; speedup 1.0000x reference)
//
#include <hip/hip_runtime.h>
#include <hip/hip_bf16.h>
#include <stdint.h>

// SimCLR loss, n=8192, d=128, T=0.07.
// R12 = R11 (fragment-major fnB: every MFMA fragment = one coalesced 1KB
// load; no LDS, no barriers in k_simexp) + SYMMETRY on that clean base.
// Triangle over 64 bands x 128: 2080 blocks (4 waves x 32 rows, 8 col
// tiles). Off-diag tiles feed row sums AND col sums (both from the same
// exp values); diag blocks do the full square with row sums only. Col
// partials live in fully-unrolled static registers; shuffles + atomicAdds
// only in the epilogue. E[8192] in L2, ~160 adds/address. Mean via
// terms[] + k_reduce (R10: same-address atomic mean = 20us, never again).
//  k_normalize: fp32 -> bf16 fn (row-major) + fnB (frag-major); blk0 zeroes E
//  k_simexp:    triangle blocks -> atomicAdd E[8192] (epilogue only)
//  k_finalize:  per-row term -> terms[];  k_reduce: mean -> out[0]

#define N_ROWS 8192
#define DIM    128
#define HALF_N 4096
#define NBANDS 64
#define BROWS  128                           // band width (rows & cols)
#define NTRI   (NBANDS * (NBANDS + 1) / 2)   // 2080 blocks
#define NJT    (BROWS / 16)                  // 8 col tiles per block

static constexpr float INV_T = 14.285714285714286f;   // 1/0.07
static constexpr float SCALE = 20.60992915555662f;    // log2(e)/0.07

typedef __attribute__((ext_vector_type(8))) short short8;   // 8 bf16 = 4 VGPR
typedef __attribute__((ext_vector_type(4))) float f32x4;

#if __has_builtin(__builtin_amdgcn_exp2f)
__device__ inline float fast_exp2(float x) { return __builtin_amdgcn_exp2f(x); }
#else
__device__ inline float fast_exp2(float x) { return exp2f(x); }
#endif

__device__ inline float bf_lo(uint32_t u) { return __uint_as_float(u << 16); }
__device__ inline float bf_hi(uint32_t u) { return __uint_as_float(u & 0xFFFF0000u); }
__device__ inline uint16_t f2bf(float x) {
    uint32_t u = __float_as_uint(x);
    return (uint16_t)((u + 0x7FFFu + ((u >> 16) & 1u)) >> 16);   // RNE
}

// fnB layout (16B chunks): chunk(row j, dim k) = (j>>4)*256 + (k>>5)*64
//   + ((k>>3)&3)*16 + (j&15); byte-in-chunk = (k&7)*2.
// Fragment load for lane l: fnB16[tile*256 + kc*64 + l] = row tile*16+(l&15),
// dims kc*32+(l>>4)*8..+8.  A and B fragments are identical gathers.

// ---------------- kernel 1: normalize -> fn + fnB; zero E -----------------
__global__ __launch_bounds__(256) void k_normalize(const float* __restrict__ f,
                                                   uint16_t* __restrict__ fn,
                                                   uint16_t* __restrict__ fnB,
                                                   float* __restrict__ E) {
    if (blockIdx.x == 0) {                 // zero E before k_simexp runs
        float4 z = {0.f, 0.f, 0.f, 0.f};
        #pragma unroll
        for (int i = 0; i < 8; ++i)
            ((float4*)E)[threadIdx.x + i * 256] = z;
    }
    int wid  = (blockIdx.x * blockDim.x + threadIdx.x) >> 6;   // one wave per row
    int lane = threadIdx.x & 63;
    const float2* src = (const float2*)(f + (size_t)wid * DIM);
    float2 v = src[lane];
    float ss = v.x * v.x + v.y * v.y;
    #pragma unroll
    for (int m = 1; m < 64; m <<= 1) ss += __shfl_xor(ss, m, 64);
    float inv = rsqrtf(ss);
    ushort2 o;
    o.x = f2bf(v.x * inv);
    o.y = f2bf(v.y * inv);
    ((ushort2*)(fn + (size_t)wid * DIM))[lane] = o;              // row-major
    int k0 = lane * 2;                                            // frag-major
    size_t chunk = (size_t)(wid >> 4) * 256 + (k0 >> 5) * 64 +
                   ((k0 >> 3) & 3) * 16 + (wid & 15);
    *(ushort2*)((char*)fnB + chunk * 16 + (k0 & 7) * 2) = o;
}

// ---------------- kernel 2: triangle sim + exp-sum (frag-major, no LDS) ---
__global__ __launch_bounds__(256) void k_simexp(const uint16_t* __restrict__ fnB,
                                                float* __restrict__ E) {
    // decode triangular block index (SALU loop, <=64 iters)
    int bx = 0, rem = blockIdx.x;
    while (rem >= NBANDS - bx) { rem -= NBANDS - bx; ++bx; }
    const int by = bx + rem;
    const bool diag = (by == bx);

    const int lane = threadIdx.x & 63;
    const int w    = threadIdx.x >> 6;
    const int lr = lane & 15;
    const int lk = lane >> 4;
    const int ib = bx * BROWS + w * 32;        // wave's 32 rows
    const int tileA0 = ib >> 4;                // 2 row tiles
    const int tileB0 = by * NJT;               // 8 col tiles

    const short8* fnB8 = (const short8*)fnB;

    // A fragments: 2 tiles x 4 k-chunks, one coalesced 1KB load each (32 regs)
    short8 Af[2][4];
    #pragma unroll
    for (int mt = 0; mt < 2; ++mt)
        #pragma unroll
        for (int kc = 0; kc < 4; ++kc)
            Af[mt][kc] = fnB8[(size_t)(tileA0 + mt) * 256 + kc * 64 + lane];

    float es[2][4];                            // row accumulators
    #pragma unroll
    for (int mt = 0; mt < 2; ++mt)
        #pragma unroll
        for (int r = 0; r < 4; ++r) es[mt][r] = 0.0f;
    float cs_acc[NJT];                         // col partials (static idx)
    #pragma unroll
    for (int jt = 0; jt < NJT; ++jt) cs_acc[jt] = 0.0f;

    #pragma unroll
    for (int jt = 0; jt < NJT; ++jt) {
        const short8* bp = fnB8 + (size_t)(tileB0 + jt) * 256 + lane;
        short8 Bf[4];
        #pragma unroll
        for (int kc = 0; kc < 4; ++kc)
            Bf[kc] = bp[kc * 64];              // coalesced 1KB per load
        float cs = 0.0f;
        #pragma unroll
        for (int mt = 0; mt < 2; ++mt) {
            f32x4 acc = {0.0f, 0.0f, 0.0f, 0.0f};
            #pragma unroll
            for (int kc = 0; kc < 4; ++kc)
                acc = __builtin_amdgcn_mfma_f32_16x16x32_bf16(Af[mt][kc], Bf[kc], acc, 0, 0, 0);
            #pragma unroll
            for (int r = 0; r < 4; ++r) {
                float e = fast_exp2(fmaf(acc[r], SCALE, -SCALE));
                es[mt][r] += e;                // row accumulator
                cs += e;                       // col partial (wave's 32 rows)
            }
        }
        cs_acc[jt] = cs;
    }

    // epilogue: row sums (D: col=lr, row=lk*4+r; reduce over 16 col-lanes)
    #pragma unroll
    for (int mt = 0; mt < 2; ++mt)
        #pragma unroll
        for (int r = 0; r < 4; ++r) {
            float v = es[mt][r];
            v += __shfl_xor(v, 1, 64);
            v += __shfl_xor(v, 2, 64);
            v += __shfl_xor(v, 4, 64);
            v += __shfl_xor(v, 8, 64);
            if (lr == 0)
                atomicAdd(&E[ib + mt * 16 + lk * 4 + r], v);
        }
    // col sums: reduce over the 4 lk groups (rows), off-diag only
    if (!diag) {
        #pragma unroll
        for (int jt = 0; jt < NJT; ++jt) {
            float cs = cs_acc[jt];
            cs += __shfl_xor(cs, 16, 64);
            cs += __shfl_xor(cs, 32, 64);
            if (lk == 0)
                atomicAdd(&E[by * BROWS + jt * 16 + lr], cs);
        }
    }
}

// ---------------- kernel 3: per-row finalize -> block partials ------------
__global__ __launch_bounds__(256) void k_finalize(const uint16_t* __restrict__ fn,
                                                  const float* __restrict__ E,
                                                  float* __restrict__ terms) {
    __shared__ float sm[4];
    int wid  = (blockIdx.x * blockDim.x + threadIdx.x) >> 6;   // one wave per row
    int lane = threadIdx.x & 63;
    int partner = (wid + HALF_N) & (N_ROWS - 1);
    const uint32_t* fr = (const uint32_t*)(fn + (size_t)wid * DIM);
    const uint32_t* pr = (const uint32_t*)(fn + (size_t)partner * DIM);
    uint32_t a = fr[lane], p = pr[lane];
    float a0 = bf_lo(a), a1 = bf_hi(a);
    float p0 = bf_lo(p), p1 = bf_hi(p);
    float sd = a0 * a0 + a1 * a1;       // self dot (diagonal recompute)
    float pd = a0 * p0 + a1 * p1;       // positive-pair dot
    #pragma unroll
    for (int m = 1; m < 64; m <<= 1) {
        sd += __shfl_xor(sd, m, 64);
        pd += __shfl_xor(pd, m, 64);
    }
    if (lane == 0) {
        float ep = E[wid] - fast_exp2(fmaf(sd, SCALE, -SCALE));   // drop diag
        sm[threadIdx.x >> 6] = INV_T + logf(ep) - pd * INV_T;
    }
    __syncthreads();
    if (threadIdx.x == 0)
        terms[blockIdx.x] = sm[0] + sm[1] + sm[2] + sm[3];
}

// ---------------- kernel 4: mean over 2048 block partials ----------------
__global__ __launch_bounds__(256) void k_reduce(const float* __restrict__ terms,
                                                float* __restrict__ out) {
    __shared__ float sm[4];
    float acc = 0.0f;
    for (int i = threadIdx.x; i < N_ROWS / 4; i += 256) acc += terms[i];
    #pragma unroll
    for (int m = 1; m < 64; m <<= 1) acc += __shfl_xor(acc, m, 64);
    if ((threadIdx.x & 63) == 0) sm[threadIdx.x >> 6] = acc;
    __syncthreads();
    if (threadIdx.x == 0)
        out[0] = (sm[0] + sm[1] + sm[2] + sm[3]) * (1.0f / N_ROWS);
}

extern "C" void kernel_launch(void* const* d_in, const int* in_sizes, int n_in,
                              void* d_out, int out_size, void* d_ws, size_t ws_size,
                              hipStream_t stream) {
    const float* feat = (const float*)d_in[0];
    float* out = (float*)d_out;

    // ws: fn (2 MiB) | fnB (2 MiB) | E (32 KiB) | terms (8 KiB)
    uint16_t* fn  = (uint16_t*)d_ws;
    uint16_t* fnB = fn + (size_t)N_ROWS * DIM;
    float* E      = (float*)(fnB + (size_t)N_ROWS * DIM);
    float* terms  = E + N_ROWS;

    k_normalize<<<dim3(N_ROWS / 4), dim3(256), 0, stream>>>(feat, fn, fnB, E);
    k_simexp<<<dim3(NTRI), dim3(256), 0, stream>>>(fnB, E);
    k_finalize<<<dim3(N_ROWS / 4), dim3(256), 0, stream>>>(fn, E, terms);
    k_reduce<<<dim3(1), dim3(256), 0, stream>>>(terms, out);
}

// Round 13
// 38.945 us; speedup vs baseline: 1.1325x; 1.1325x over previous
//
#include <hip/hip_runtime.h>
#include <hip/hip_bf16.h>
#include <stdint.h>

// SimCLR loss, n=8192, d=128, T=0.07.
// R13 = R11 (fragment-major fnB; no LDS/barriers/atomics in k_simexp; best
// total 38.7us) + static ping-pong B prefetch. R11's rolled jt loop exposed
// ~250cy L2 latency per tile per wave (loads of jt+1 never issued until jt
// done). Now Ba/Bb named buffers (rule#20-static), jt step 2: next tile's 4
// loads are in flight during current tile's 16 MFMA + 16 exp2.
// R12 lesson (symmetry dead, 4th failure): B-reuse = rows-per-wave, so
// triangle variants conserve total load traffic while doubling prologues.
//  k_normalize: fp32 -> bf16: fn (row-major) + fnB (fragment-major)
//  k_simexp:    E_part[row][slice] = sum_j exp2((dot-1)*s)   (plain stores)
//  k_finalize:  per-row term -> terms[];  k_reduce: mean -> out[0]

#define N_ROWS 8192
#define DIM    128
#define HALF_N 4096
#define N_SLICES 32
#define NT 16                     // 16-col tiles per 256-col slice
#define ROWS_PER_BLOCK 256        // 4 waves x 64 rows

static constexpr float INV_T = 14.285714285714286f;   // 1/0.07
static constexpr float SCALE = 20.60992915555662f;    // log2(e)/0.07

typedef __attribute__((ext_vector_type(8))) short short8;   // 8 bf16 = 4 VGPR
typedef __attribute__((ext_vector_type(4))) float f32x4;

#if __has_builtin(__builtin_amdgcn_exp2f)
__device__ inline float fast_exp2(float x) { return __builtin_amdgcn_exp2f(x); }
#else
__device__ inline float fast_exp2(float x) { return exp2f(x); }
#endif

__device__ inline float bf_lo(uint32_t u) { return __uint_as_float(u << 16); }
__device__ inline float bf_hi(uint32_t u) { return __uint_as_float(u & 0xFFFF0000u); }
__device__ inline uint16_t f2bf(float x) {
    uint32_t u = __float_as_uint(x);
    return (uint16_t)((u + 0x7FFFu + ((u >> 16) & 1u)) >> 16);   // RNE
}

// fnB layout (16B chunks): chunk(row j, dim k) = (j>>4)*256 + (k>>5)*64
//   + ((k>>3)&3)*16 + (j&15); byte-in-chunk = (k&7)*2.
// Fragment load for lane l: fnB16[tile*256 + kc*64 + l] = row tile*16+(l&15),
// dims kc*32+(l>>4)*8..+8.  A and B fragments are identical gathers.

// ---------------- kernel 1: normalize -> fn (row-major) + fnB (frag) ------
__global__ __launch_bounds__(256) void k_normalize(const float* __restrict__ f,
                                                   uint16_t* __restrict__ fn,
                                                   uint16_t* __restrict__ fnB) {
    int wid  = (blockIdx.x * blockDim.x + threadIdx.x) >> 6;   // one wave per row
    int lane = threadIdx.x & 63;
    const float2* src = (const float2*)(f + (size_t)wid * DIM);
    float2 v = src[lane];
    float ss = v.x * v.x + v.y * v.y;
    #pragma unroll
    for (int m = 1; m < 64; m <<= 1) ss += __shfl_xor(ss, m, 64);
    float inv = rsqrtf(ss);
    ushort2 o;
    o.x = f2bf(v.x * inv);
    o.y = f2bf(v.y * inv);
    ((ushort2*)(fn + (size_t)wid * DIM))[lane] = o;              // row-major
    int k0 = lane * 2;                                            // frag-major
    size_t chunk = (size_t)(wid >> 4) * 256 + (k0 >> 5) * 64 +
                   ((k0 >> 3) & 3) * 16 + (wid & 15);
    *(ushort2*)((char*)fnB + chunk * 16 + (k0 & 7) * 2) = o;
}

// ---------------- kernel 2: sim + exp-sum, pipelined fragment loads -------
// Grid (32, 32): block = 4 waves x 64 rows = 256 rows, 256 cols (16 tiles).
__global__ __launch_bounds__(256) void k_simexp(const uint16_t* __restrict__ fnB,
                                                float* __restrict__ E_part) {
    const int lane  = threadIdx.x & 63;
    const int w     = threadIdx.x >> 6;
    const int ib    = blockIdx.x * ROWS_PER_BLOCK + w * 64;
    const int slice = blockIdx.y;
    const int lr = lane & 15;
    const int lk = lane >> 4;

    const short8* fnB8 = (const short8*)fnB;   // 16B chunks
    const int tileA0 = ib >> 4;
    const int jt0    = slice * NT;             // first B tile of this slice

    // A fragments: one coalesced 1KB load each (16 total, 64 regs)
    short8 Af[4][4];
    #pragma unroll
    for (int mt = 0; mt < 4; ++mt)
        #pragma unroll
        for (int kc = 0; kc < 4; ++kc)
            Af[mt][kc] = fnB8[(size_t)(tileA0 + mt) * 256 + kc * 64 + lane];

    float es[4][4];
    #pragma unroll
    for (int mt = 0; mt < 4; ++mt)
        #pragma unroll
        for (int r = 0; r < 4; ++r) es[mt][r] = 0.0f;

    const short8* bbase = fnB8 + (size_t)jt0 * 256 + lane;

    // 16 MFMA + 16 exp2 on tile B; es accumulation
    #define COMPUTE(B)                                                        \
        _Pragma("unroll")                                                     \
        for (int mt = 0; mt < 4; ++mt) {                                      \
            f32x4 acc = {0.0f, 0.0f, 0.0f, 0.0f};                             \
            _Pragma("unroll")                                                 \
            for (int kc = 0; kc < 4; ++kc)                                    \
                acc = __builtin_amdgcn_mfma_f32_16x16x32_bf16(Af[mt][kc],     \
                                                    (B)[kc], acc, 0, 0, 0);   \
            _Pragma("unroll")                                                 \
            for (int r = 0; r < 4; ++r)                                       \
                es[mt][r] += fast_exp2(fmaf(acc[r], SCALE, -SCALE));          \
        }

    short8 Ba[4], Bb[4];                       // static ping-pong (rule #20)
    #pragma unroll
    for (int kc = 0; kc < 4; ++kc) Ba[kc] = bbase[kc * 64];

    for (int jt = 0; jt < NT; jt += 2) {
        const short8* bp1 = bbase + (size_t)(jt + 1) * 256;
        #pragma unroll
        for (int kc = 0; kc < 4; ++kc) Bb[kc] = bp1[kc * 64];   // prefetch jt+1
        COMPUTE(Ba)                                             // compute jt
        if (jt + 2 < NT) {
            const short8* bp2 = bbase + (size_t)(jt + 2) * 256;
            #pragma unroll
            for (int kc = 0; kc < 4; ++kc) Ba[kc] = bp2[kc * 64]; // prefetch jt+2
        }
        COMPUTE(Bb)                                             // compute jt+1
    }
    #undef COMPUTE

    // C/D: col = lane&15 (= B row j), row = lk*4 + r. Reduce over col-lanes.
    #pragma unroll
    for (int mt = 0; mt < 4; ++mt)
        #pragma unroll
        for (int r = 0; r < 4; ++r) {
            float v = es[mt][r];
            v += __shfl_xor(v, 1, 64);
            v += __shfl_xor(v, 2, 64);
            v += __shfl_xor(v, 4, 64);
            v += __shfl_xor(v, 8, 64);
            if (lr == 0)
                E_part[(size_t)(ib + mt * 16 + lk * 4 + r) * N_SLICES + slice] = v;
        }
}

// ---------------- kernel 3: per-row finalize -> block partials ------------
__global__ __launch_bounds__(256) void k_finalize(const uint16_t* __restrict__ fn,
                                                  const float* __restrict__ E_part,
                                                  float* __restrict__ terms) {
    __shared__ float sm[4];
    int wid  = (blockIdx.x * blockDim.x + threadIdx.x) >> 6;   // one wave per row
    int lane = threadIdx.x & 63;
    int partner = (wid + HALF_N) & (N_ROWS - 1);
    const uint32_t* fr = (const uint32_t*)(fn + (size_t)wid * DIM);
    const uint32_t* pr = (const uint32_t*)(fn + (size_t)partner * DIM);
    uint32_t a = fr[lane], p = pr[lane];
    float a0 = bf_lo(a), a1 = bf_hi(a);
    float p0 = bf_lo(p), p1 = bf_hi(p);
    float sd = a0 * a0 + a1 * a1;       // self dot (diagonal recompute)
    float pd = a0 * p0 + a1 * p1;       // positive-pair dot
    #pragma unroll
    for (int m = 1; m < 64; m <<= 1) {
        sd += __shfl_xor(sd, m, 64);
        pd += __shfl_xor(pd, m, 64);
    }
    float e = (lane < N_SLICES) ? E_part[(size_t)wid * N_SLICES + lane] : 0.0f;
    #pragma unroll
    for (int m = 1; m < 64; m <<= 1) e += __shfl_xor(e, m, 64);
    if (lane == 0) {
        float ep = e - fast_exp2(fmaf(sd, SCALE, -SCALE));   // remove diagonal
        sm[threadIdx.x >> 6] = INV_T + logf(ep) - pd * INV_T;
    }
    __syncthreads();
    if (threadIdx.x == 0)
        terms[blockIdx.x] = sm[0] + sm[1] + sm[2] + sm[3];
}

// ---------------- kernel 4: mean over 2048 block partials ----------------
__global__ __launch_bounds__(256) void k_reduce(const float* __restrict__ terms,
                                                float* __restrict__ out) {
    __shared__ float sm[4];
    float acc = 0.0f;
    for (int i = threadIdx.x; i < N_ROWS / 4; i += 256) acc += terms[i];
    #pragma unroll
    for (int m = 1; m < 64; m <<= 1) acc += __shfl_xor(acc, m, 64);
    if ((threadIdx.x & 63) == 0) sm[threadIdx.x >> 6] = acc;
    __syncthreads();
    if (threadIdx.x == 0)
        out[0] = (sm[0] + sm[1] + sm[2] + sm[3]) * (1.0f / N_ROWS);
}

extern "C" void kernel_launch(void* const* d_in, const int* in_sizes, int n_in,
                              void* d_out, int out_size, void* d_ws, size_t ws_size,
                              hipStream_t stream) {
    const float* feat = (const float*)d_in[0];
    float* out = (float*)d_out;

    // ws: fn (2 MiB) | fnB (2 MiB) | E_part (1 MiB) | terms (8 KiB)
    uint16_t* fn  = (uint16_t*)d_ws;
    uint16_t* fnB = fn + (size_t)N_ROWS * DIM;
    float* E_part = (float*)(fnB + (size_t)N_ROWS * DIM);
    float* terms  = E_part + (size_t)N_ROWS * N_SLICES;

    k_normalize<<<dim3(N_ROWS / 4), dim3(256), 0, stream>>>(feat, fn, fnB);
    k_simexp<<<dim3(N_ROWS / ROWS_PER_BLOCK, N_SLICES), dim3(256), 0, stream>>>(fnB, E_part);
    k_finalize<<<dim3(N_ROWS / 4), dim3(256), 0, stream>>>(fn, E_part, terms);
    k_reduce<<<dim3(1), dim3(256), 0, stream>>>(terms, out);
}